// Round 1
// baseline (178.783 us; speedup 1.0000x reference)
//
#include <hip/hip_runtime.h>
#include <hip/hip_bf16.h>
#include <math.h>

// AdaptedEntropyBottleneck on MI355X.
// Shapes (fixed by setup_inputs): x [16,192,64,64] fp32, codebook [64] fp32 sorted,
// MLP params per channel: 1->3->3->3->3->1 with softplus(weights), tanh gates.
// Outputs: y_hat [N,C,H,W] then lik [N,C,H,W], concatenated flat in d_out (fp32).
//
// Strategy: lik depends only on (channel, codebook index) -> precompute a
// C*K = 192*64 = 12288-entry table in d_ws, then the main pass is a
// memory-bound quantize + 2x gather (roofline ~151 MB HBM traffic ~ 24 us).

#define CCH 192
#define KCB 64

__device__ __forceinline__ float softplusf_(float x) {
    // jax.nn.softplus = logaddexp(x, 0) = max(x,0) + log1p(exp(-|x|))
    return fmaxf(x, 0.0f) + log1pf(expf(-fabsf(x)));
}
__device__ __forceinline__ float sigmoidf_(float x) {
    return 1.0f / (1.0f + expf(-x));
}

__global__ __launch_bounds__(256) void build_table(
        const float* __restrict__ cb,
        const float* __restrict__ m0, const float* __restrict__ b0, const float* __restrict__ f0,
        const float* __restrict__ m1, const float* __restrict__ b1, const float* __restrict__ f1,
        const float* __restrict__ m2, const float* __restrict__ b2, const float* __restrict__ f2,
        const float* __restrict__ m3, const float* __restrict__ b3, const float* __restrict__ f3,
        const float* __restrict__ m4, const float* __restrict__ b4,
        float* __restrict__ table) {
    int t = blockIdx.x * blockDim.x + threadIdx.x;
    if (t >= CCH * KCB) return;
    int c = t >> 6;   // channel
    int k = t & 63;   // codebook index

    float y  = cb[k];
    float vl = y - 0.5f;
    float vu = y + 0.5f;

    float hl[3], hu[3];
    // layer 0: (C,3,1) weights
    #pragma unroll
    for (int j = 0; j < 3; ++j) {
        float w = softplusf_(m0[c * 3 + j]);
        float b = b0[c * 3 + j];
        float a = tanhf(f0[c * 3 + j]);
        float zl = w * vl + b; zl = zl + a * tanhf(zl);
        float zu = w * vu + b; zu = zu + a * tanhf(zu);
        hl[j] = zl; hu[j] = zu;
    }
    // layers 1..3: (C,3,3) weights
    const float* Ms[3] = {m1, m2, m3};
    const float* Bs[3] = {b1, b2, b3};
    const float* Fs[3] = {f1, f2, f3};
    #pragma unroll
    for (int L = 0; L < 3; ++L) {
        float nl[3], nu[3];
        #pragma unroll
        for (int j = 0; j < 3; ++j) {
            float zl = 0.0f, zu = 0.0f;
            #pragma unroll
            for (int i = 0; i < 3; ++i) {
                float w = softplusf_(Ms[L][(c * 3 + j) * 3 + i]);
                zl += w * hl[i];
                zu += w * hu[i];
            }
            float b = Bs[L][c * 3 + j];
            zl += b; zu += b;
            float a = tanhf(Fs[L][c * 3 + j]);
            zl = zl + a * tanhf(zl);
            zu = zu + a * tanhf(zu);
            nl[j] = zl; nu[j] = zu;
        }
        #pragma unroll
        for (int j = 0; j < 3; ++j) { hl[j] = nl[j]; hu[j] = nu[j]; }
    }
    // layer 4: (C,1,3) weights, bias (C,1,1)
    float lower = 0.0f, upper = 0.0f;
    #pragma unroll
    for (int i = 0; i < 3; ++i) {
        float w = softplusf_(m4[c * 3 + i]);
        lower += w * hl[i];
        upper += w * hu[i];
    }
    lower += b4[c];
    upper += b4[c];

    float s  = lower + upper;
    float sg = (s > 0.0f) ? -1.0f : ((s < 0.0f) ? 1.0f : 0.0f);
    float lik = fabsf(sigmoidf_(sg * upper) - sigmoidf_(sg * lower));
    lik = fmaxf(lik, 1e-9f);
    table[t] = lik;
}

// Each block: 256 threads * 4 elems = 1024 consecutive elements.
// H*W = 4096 -> every block lies entirely within one (n,c) slice:
// c = (blockIdx.x >> 2) % 192, block-uniform.
__global__ __launch_bounds__(256) void eb_main(
        const float* __restrict__ x,
        const float* __restrict__ cb,
        const float* __restrict__ table,
        float* __restrict__ out,
        int nvec) {
    __shared__ float s_cb[KCB];
    __shared__ float s_lik[KCB];
    const int tid = threadIdx.x;
    const int c = (blockIdx.x >> 2) % CCH;
    if (tid < 64) {
        s_cb[tid] = cb[tid];
    } else if (tid < 128) {
        s_lik[tid - 64] = table[c * 64 + (tid - 64)];
    }
    __syncthreads();

    const int e4 = blockIdx.x * 256 + tid;   // float4 index
    if (e4 >= nvec) return;
    const float4 xv = ((const float4*)x)[e4];

    float xs[4] = {xv.x, xv.y, xv.z, xv.w};
    float ys[4], ls[4];
    #pragma unroll
    for (int q = 0; q < 4; ++q) {
        const float xx = xs[q];
        // searchsorted(cb, xx, side='left') over 64 entries: 6 steps
        int lo = 0, hi = 64;
        #pragma unroll
        for (int it = 0; it < 6; ++it) {
            int mid = (lo + hi) >> 1;
            if (s_cb[mid] < xx) lo = mid + 1; else hi = mid;
        }
        const int i  = lo;                       // insertion point in [0,64]
        int il = i - 1; il = (il < 0) ? 0 : il; il = (il > 63) ? 63 : il;
        const int ih = (i > 63) ? 63 : i;
        const float cl = s_cb[il];
        const float ch = s_cb[ih];
        // reference tie-break: pick hi iff |cb[hi]-x| < |cb[lo]-x| (strict)
        const int idx = (fabsf(ch - xx) < fabsf(cl - xx)) ? ih : il;
        ys[q] = s_cb[idx];
        ls[q] = s_lik[idx];
    }

    ((float4*)out)[e4]        = make_float4(ys[0], ys[1], ys[2], ys[3]);
    ((float4*)out)[nvec + e4] = make_float4(ls[0], ls[1], ls[2], ls[3]);
}

extern "C" void kernel_launch(void* const* d_in, const int* in_sizes, int n_in,
                              void* d_out, int out_size, void* d_ws, size_t ws_size,
                              hipStream_t stream) {
    // setup_inputs dict order:
    // 0:x 1:codebook 2:m0 3:b0 4:f0 5:m1 6:b1 7:f1 8:m2 9:b2 10:f2
    // 11:m3 12:b3 13:f3 14:m4 15:b4
    const float* x  = (const float*)d_in[0];
    const float* cb = (const float*)d_in[1];
    const float* m0 = (const float*)d_in[2];
    const float* b0 = (const float*)d_in[3];
    const float* f0 = (const float*)d_in[4];
    const float* m1 = (const float*)d_in[5];
    const float* b1 = (const float*)d_in[6];
    const float* f1 = (const float*)d_in[7];
    const float* m2 = (const float*)d_in[8];
    const float* b2 = (const float*)d_in[9];
    const float* f2 = (const float*)d_in[10];
    const float* b3_ = (const float*)d_in[12];
    const float* m3 = (const float*)d_in[11];
    const float* f3 = (const float*)d_in[13];
    const float* m4 = (const float*)d_in[14];
    const float* b4 = (const float*)d_in[15];

    float* table = (float*)d_ws;   // 12288 floats = 48 KB

    build_table<<<(CCH * KCB + 255) / 256, 256, 0, stream>>>(
        cb, m0, b0, f0, m1, b1, f1, m2, b2, f2, m3, b3_, f3, m4, b4, table);

    const int total = in_sizes[0];         // 12,582,912
    const int nvec  = total / 4;           // 3,145,728 float4s
    const int blocks = nvec / 256;         // 12,288 blocks (exact)
    eb_main<<<blocks, 256, 0, stream>>>(x, cb, table, (float*)d_out, nvec);
}